// Round 8
// baseline (269.093 us; speedup 1.0000x reference)
//
#include <hip/hip_runtime.h>
#include <math.h>

#define BB 4
#define CC 256
#define HH 512
#define WW 256
#define CRED 64
#define GIN 4
#define KNN8 8

typedef float f4 __attribute__((ext_vector_type(4)));

__device__ __forceinline__ float wave_sum(float v) {
#pragma unroll
    for (int off = 32; off; off >>= 1) v += __shfl_xor(v, off, 64);
    return v;
}

// ---------- kernel 1a: per-row mean, mirrored on the proven writer shape ----------
// one wave per contiguous 1KB input row, gid order == linear address order.
__global__ __launch_bounds__(256) void rowmean_kernel(const float* __restrict__ x,
                                                      float* __restrict__ M) {
    int gid  = blockIdx.x * 256 + threadIdx.x;   // over B*C*H*64
    int row  = gid >> 6;                         // (b*C + c)*H + h, 524288 rows
    int lane = threadIdx.x & 63;
    const f4 v = __builtin_nontemporal_load((const f4*)(x + (size_t)row * WW + lane * 4));
    float s = wave_sum(v.x + v.y + v.z + v.w);
    if (lane == 0) M[row] = s * (1.f / 256.f);
}

// ---------- kernel 1b: grouped reduce from M (2 MB, L2-resident) ----------
// one wave per (b,h); lane = o. Xr layout [B][H][CRED].
__global__ __launch_bounds__(256) void greduce_kernel(const float* __restrict__ M,
                                                      const float* __restrict__ Wr,
                                                      float* __restrict__ Xr) {
    int gid  = blockIdx.x * 256 + threadIdx.x;
    int wid  = gid >> 6;                  // (b<<9)+h, over 2048
    int lane = threadIdx.x & 63;          // o
    int b = wid >> 9, h = wid & 511;
    const float* Mb = M + (size_t)b * CC * HH;
    float s = 0.f;
#pragma unroll
    for (int g = 0; g < GIN; ++g)
        s += Wr[lane * GIN + g] * Mb[(lane * GIN + g) * HH + h];
    Xr[(wid << 6) + lane] = s;
}

// ---------- kernel 2: normalize Uk rows (bit-identical) ----------
__global__ __launch_bounds__(256) void normalize_kernel(const float* __restrict__ Uk,
                                                        float* __restrict__ Un) {
    int gid  = blockIdx.x * 256 + threadIdx.x;
    int wid  = gid >> 6;          // over B*H = 2048
    int lane = threadIdx.x & 63;
    float v  = Uk[wid * 64 + lane];
    float ss = wave_sum(v * v);
    float norm = fmaxf(sqrtf(ss), 1e-12f);
    Un[wid * 64 + lane] = v / norm;
}

// ---------- kernel 3: cosine sim + stable top-8 + degree (bit-identical) ----------
__global__ __launch_bounds__(256) void topk_kernel(const float* __restrict__ Un,
                                                   float* __restrict__ topv,
                                                   int* __restrict__ topi,
                                                   float* __restrict__ deg) {
    int gid  = blockIdx.x * 256 + threadIdx.x;
    int wid  = gid >> 6;          // over B*H = 2048
    int lane = threadIdx.x & 63;
    int b = wid >> 9;
    const float* Ub = Un + b * HH * 64;
    const float* uh = Un + wid * 64;

    float sim[8];
#pragma unroll
    for (int j = 0; j < 8; ++j) sim[j] = 0.f;
#pragma unroll 4
    for (int kk = 0; kk < 64; ++kk) {
        float uhv = uh[kk];
#pragma unroll
        for (int j = 0; j < 8; ++j) sim[j] += uhv * Ub[(lane + 64 * j) * 64 + kk];
    }

    float vsum = 0.f;
#pragma unroll
    for (int r = 0; r < KNN8; ++r) {
        float bv = sim[0]; int bj = 0;
#pragma unroll
        for (int j = 1; j < 8; ++j) { if (sim[j] > bv) { bv = sim[j]; bj = j; } }
        float v = bv; int g = lane + 64 * bj;
#pragma unroll
        for (int off = 32; off; off >>= 1) {
            float ov = __shfl_xor(v, off, 64);
            int   og = __shfl_xor(g, off, 64);
            if (ov > v || (ov == v && og < g)) { v = ov; g = og; }
        }
        vsum += v;
        if (lane == 0) { topv[wid * KNN8 + r] = v; topi[wid * KNN8 + r] = g; }
        if ((g & 63) == lane) sim[g >> 6] = -INFINITY;
    }
    if (lane == 0) deg[wid] = vsum;
}

// ---------- kernel 4: neighbor-aggregate + GCN matmul + bias/relu (bit-identical) ----------
__global__ __launch_bounds__(64) void gcnval_kernel(const float* __restrict__ Xr,
                                                    const float* __restrict__ Wg,
                                                    const float* __restrict__ bg,
                                                    const float* __restrict__ topv,
                                                    const int* __restrict__ topi,
                                                    const float* __restrict__ deg,
                                                    float* __restrict__ yout) {
    int bh   = blockIdx.x;            // (b<<9) + h
    int b    = bh >> 9;
    int lane = threadIdx.x & 63;

    float dh = 1.0f / sqrtf(deg[bh]);
    float z = 0.f;
#pragma unroll
    for (int k = 0; k < KNN8; ++k) {
        int   i = topi[bh * KNN8 + k];
        float w = topv[bh * KNN8 + k] * dh * (1.0f / sqrtf(deg[(b << 9) + i]));
        z += w * Xr[(((b << 9) + i) << 6) + lane];
    }
    float y = 0.f;
#pragma unroll 16
    for (int c = 0; c < CRED; ++c) y += __shfl(z, c, 64) * Wg[c * CRED + lane];
    yout[(bh << 6) + lane] = fmaxf(y + bg[lane], 0.f);
}

// ---------- kernel 5: linear writer, one contiguous 1KB row per wave, nt stores (bit-identical) ----------
__global__ __launch_bounds__(256) void out_kernel(const float* __restrict__ yout,
                                                  const float* __restrict__ We,
                                                  float* __restrict__ out) {
    int gid = blockIdx.x * 256 + threadIdx.x;   // over B*C*H*64
    int row = gid >> 6;                         // (b*C + c)*H + h
    int w4  = gid & 63;
    int h = row & 511;
    int c = (row >> 9) & 255;
    int b = row >> 17;
    float val = yout[(((b << 9) + h) << 6) + (c >> 2)] * We[c];
    f4 v = {val, val, val, val};
    __builtin_nontemporal_store(v, (f4*)(out + (size_t)row * WW + w4 * 4));
}

extern "C" void kernel_launch(void* const* d_in, const int* in_sizes, int n_in,
                              void* d_out, int out_size, void* d_ws, size_t ws_size,
                              hipStream_t stream) {
    const float* x  = (const float*)d_in[0];
    const float* Uk = (const float*)d_in[1];
    const float* Wr = (const float*)d_in[2];
    const float* Wg = (const float*)d_in[3];
    const float* bg = (const float*)d_in[4];
    const float* We = (const float*)d_in[5];
    float* out = (float*)d_out;
    float* ws  = (float*)d_ws;

    float* Xr   = ws;                 // B*H*64   = 131072
    float* Un   = ws + 131072;        // B*H*64   = 131072
    float* topv = ws + 262144;        // B*H*8    = 16384
    int*   topi = (int*)(ws + 278528);// B*H*8    = 16384
    float* deg  = ws + 294912;        // B*H      = 2048
    float* yout = ws + 296960;        // B*H*64   = 131072
    float* M    = ws + 428032;        // B*C*H    = 524288

    hipLaunchKernelGGL(normalize_kernel, dim3(512),    dim3(256), 0, stream, Uk, Un);
    hipLaunchKernelGGL(rowmean_kernel,   dim3(131072), dim3(256), 0, stream, x, M);
    hipLaunchKernelGGL(greduce_kernel,   dim3(512),    dim3(256), 0, stream, M, Wr, Xr);
    hipLaunchKernelGGL(topk_kernel,      dim3(512),    dim3(256), 0, stream, Un, topv, topi, deg);
    hipLaunchKernelGGL(gcnval_kernel,    dim3(2048),   dim3(64),  0, stream, Xr, Wg, bg, topv, topi, deg, yout);
    hipLaunchKernelGGL(out_kernel,       dim3(131072), dim3(256), 0, stream, yout, We, out);
}

// Round 9
// 195.187 us; speedup vs baseline: 1.3786x; 1.3786x over previous
//
#include <hip/hip_runtime.h>
#include <math.h>

#define BB 4
#define CC 256
#define HH 512
#define WW 256
#define CRED 64
#define GIN 4
#define KNN8 8

typedef float f4 __attribute__((ext_vector_type(4)));

__device__ __forceinline__ float wave_sum(float v) {
#pragma unroll
    for (int off = 32; off; off >>= 1) v += __shfl_xor(v, off, 64);
    return v;
}

// ---------- kernel 1: fused mean over W + grouped reduce (bit-identical to R6 best) ----------
// grid-stride: 8192 waves x 16 rows (full unroll -> 64 loads in flight). Xr layout [B][H][CRED].
__global__ __launch_bounds__(256) void mean_reduce_kernel(const float* __restrict__ x,
                                                          const float* __restrict__ Wr,
                                                          float* __restrict__ Xr) {
    int wgid = (blockIdx.x * 256 + threadIdx.x) >> 6;   // 0..8191
    int lane = threadIdx.x & 63;
#pragma unroll
    for (int it = 0; it < 16; ++it) {
        int row = wgid + (it << 13);                    // over B*64*H = 131072 (b,o,h) tuples
        int h = row & 511;
        int o = (row >> 9) & 63;
        int b = row >> 15;
        float s = 0.f;
#pragma unroll
        for (int g = 0; g < GIN; ++g) {
            const f4 v = __builtin_nontemporal_load(
                (const f4*)(x + ((size_t)((b * CC + o * GIN + g) * HH + h)) * WW + lane * 4));
            s += Wr[o * GIN + g] * (v.x + v.y + v.z + v.w);
        }
        s = wave_sum(s);
        if (lane == 0) Xr[((((b << 9) + h) << 6)) + o] = s * (1.f / 256.f);
    }
}

// ---------- kernel 2: normalize Uk rows, store TRANSPOSED UnT[b][k][h'] ----------
// same values as before, different layout (store side is tiny; load side of topk becomes coalesced)
__global__ __launch_bounds__(256) void normalize_kernel(const float* __restrict__ Uk,
                                                        float* __restrict__ UnT) {
    int gid  = blockIdx.x * 256 + threadIdx.x;
    int wid  = gid >> 6;          // over B*H = 2048
    int lane = threadIdx.x & 63;  // k
    int b = wid >> 9, h = wid & 511;
    float v  = Uk[wid * 64 + lane];
    float ss = wave_sum(v * v);
    float norm = fmaxf(sqrtf(ss), 1e-12f);
    UnT[(b << 15) + (lane << 9) + h] = v / norm;   // [b][k][h]
}

// ---------- kernel 3: cosine sim (coalesced via UnT) + stable top-8 + degree ----------
// bit-identical arithmetic/order to the passing version; only the load layout changed.
__global__ __launch_bounds__(256) void topk_kernel(const float* __restrict__ UnT,
                                                   float* __restrict__ topv,
                                                   int* __restrict__ topi,
                                                   float* __restrict__ deg) {
    int gid  = blockIdx.x * 256 + threadIdx.x;
    int wid  = gid >> 6;          // over B*H = 2048
    int lane = threadIdx.x & 63;
    int b = wid >> 9, h = wid & 511;
    const float* Tb = UnT + (b << 15);   // [k][h'] : 64 x 512

    // lane's own uh component: uhv = Un[b][h][lane] = UnT[b][lane][h]
    float uhv = Tb[(lane << 9) + h];

    float sim[8];
#pragma unroll
    for (int j = 0; j < 8; ++j) sim[j] = 0.f;
#pragma unroll 4
    for (int kk = 0; kk < 64; ++kk) {
        float u = __shfl(uhv, kk, 64);                 // = uh[kk], same value as before
        const float* Trow = Tb + (kk << 9);
#pragma unroll
        for (int j = 0; j < 8; ++j) sim[j] += u * Trow[lane + 64 * j];   // 4B lane stride
    }

    float vsum = 0.f;
#pragma unroll
    for (int r = 0; r < KNN8; ++r) {
        float bv = sim[0]; int bj = 0;
#pragma unroll
        for (int j = 1; j < 8; ++j) { if (sim[j] > bv) { bv = sim[j]; bj = j; } }
        float v = bv; int g = lane + 64 * bj;
#pragma unroll
        for (int off = 32; off; off >>= 1) {
            float ov = __shfl_xor(v, off, 64);
            int   og = __shfl_xor(g, off, 64);
            if (ov > v || (ov == v && og < g)) { v = ov; g = og; }
        }
        vsum += v;
        if (lane == 0) { topv[wid * KNN8 + r] = v; topi[wid * KNN8 + r] = g; }
        if ((g & 63) == lane) sim[g >> 6] = -INFINITY;
    }
    if (lane == 0) deg[wid] = vsum;
}

// ---------- kernel 4: neighbor-aggregate + GCN matmul + bias/relu (bit-identical) ----------
__global__ __launch_bounds__(64) void gcnval_kernel(const float* __restrict__ Xr,
                                                    const float* __restrict__ Wg,
                                                    const float* __restrict__ bg,
                                                    const float* __restrict__ topv,
                                                    const int* __restrict__ topi,
                                                    const float* __restrict__ deg,
                                                    float* __restrict__ yout) {
    int bh   = blockIdx.x;            // (b<<9) + h
    int b    = bh >> 9;
    int lane = threadIdx.x & 63;

    float dh = 1.0f / sqrtf(deg[bh]);
    float z = 0.f;
#pragma unroll
    for (int k = 0; k < KNN8; ++k) {
        int   i = topi[bh * KNN8 + k];
        float w = topv[bh * KNN8 + k] * dh * (1.0f / sqrtf(deg[(b << 9) + i]));
        z += w * Xr[(((b << 9) + i) << 6) + lane];
    }
    float y = 0.f;
#pragma unroll 16
    for (int c = 0; c < CRED; ++c) y += __shfl(z, c, 64) * Wg[c * CRED + lane];
    yout[(bh << 6) + lane] = fmaxf(y + bg[lane], 0.f);
}

// ---------- kernel 5: linear writer, one contiguous 1KB row per wave, nt stores (bit-identical) ----------
__global__ __launch_bounds__(256) void out_kernel(const float* __restrict__ yout,
                                                  const float* __restrict__ We,
                                                  float* __restrict__ out) {
    int gid = blockIdx.x * 256 + threadIdx.x;   // over B*C*H*64
    int row = gid >> 6;                         // (b*C + c)*H + h
    int w4  = gid & 63;
    int h = row & 511;
    int c = (row >> 9) & 255;
    int b = row >> 17;
    float val = yout[(((b << 9) + h) << 6) + (c >> 2)] * We[c];
    f4 v = {val, val, val, val};
    __builtin_nontemporal_store(v, (f4*)(out + (size_t)row * WW + w4 * 4));
}

extern "C" void kernel_launch(void* const* d_in, const int* in_sizes, int n_in,
                              void* d_out, int out_size, void* d_ws, size_t ws_size,
                              hipStream_t stream) {
    const float* x  = (const float*)d_in[0];
    const float* Uk = (const float*)d_in[1];
    const float* Wr = (const float*)d_in[2];
    const float* Wg = (const float*)d_in[3];
    const float* bg = (const float*)d_in[4];
    const float* We = (const float*)d_in[5];
    float* out = (float*)d_out;
    float* ws  = (float*)d_ws;

    float* Xr   = ws;                 // B*H*64 = 131072
    float* UnT  = ws + 131072;        // B*64*H = 131072
    float* topv = ws + 262144;        // B*H*8  = 16384
    int*   topi = (int*)(ws + 278528);// B*H*8  = 16384
    float* deg  = ws + 294912;        // B*H    = 2048
    float* yout = ws + 296960;        // B*H*64 = 131072

    hipLaunchKernelGGL(mean_reduce_kernel, dim3(2048),   dim3(256), 0, stream, x, Wr, Xr);
    hipLaunchKernelGGL(normalize_kernel,   dim3(512),    dim3(256), 0, stream, Uk, UnT);
    hipLaunchKernelGGL(topk_kernel,        dim3(512),    dim3(256), 0, stream, UnT, topv, topi, deg);
    hipLaunchKernelGGL(gcnval_kernel,      dim3(2048),   dim3(64),  0, stream, Xr, Wg, bg, topv, topi, deg, yout);
    hipLaunchKernelGGL(out_kernel,         dim3(131072), dim3(256), 0, stream, yout, We, out);
}

// Round 10
// 194.784 us; speedup vs baseline: 1.3815x; 1.0021x over previous
//
#include <hip/hip_runtime.h>
#include <math.h>

#define BB 4
#define CC 256
#define HH 512
#define WW 256
#define CRED 64
#define GIN 4
#define KNN8 8

typedef float f4 __attribute__((ext_vector_type(4)));

__device__ __forceinline__ float wave_sum(float v) {
#pragma unroll
    for (int off = 32; off; off >>= 1) v += __shfl_xor(v, off, 64);
    return v;
}

// ---------- kernel 1: [blocks 0..511] normalize Uk -> UnT ; [blocks 512..2559] mean+reduce ----------
// normalize hides under the 78us read stream; reader body bit-identical to R9 best.
__global__ __launch_bounds__(256) void k1_kernel(const float* __restrict__ x,
                                                 const float* __restrict__ Wr,
                                                 const float* __restrict__ Uk,
                                                 float* __restrict__ Xr,
                                                 float* __restrict__ UnT) {
    if (blockIdx.x < 512) {
        int gid  = blockIdx.x * 256 + threadIdx.x;
        int wid  = gid >> 6;          // over B*H = 2048
        int lane = threadIdx.x & 63;  // k
        int b = wid >> 9, h = wid & 511;
        float v  = Uk[wid * 64 + lane];
        float ss = wave_sum(v * v);
        float norm = fmaxf(sqrtf(ss), 1e-12f);
        UnT[(b << 15) + (lane << 9) + h] = v / norm;   // [b][k][h]
        return;
    }
    int wgid = ((blockIdx.x - 512) * 256 + threadIdx.x) >> 6;   // 0..8191
    int lane = threadIdx.x & 63;
#pragma unroll
    for (int it = 0; it < 16; ++it) {
        int row = wgid + (it << 13);                    // over B*64*H = 131072 (b,o,h) tuples
        int h = row & 511;
        int o = (row >> 9) & 63;
        int b = row >> 15;
        float s = 0.f;
#pragma unroll
        for (int g = 0; g < GIN; ++g) {
            const f4 v = __builtin_nontemporal_load(
                (const f4*)(x + ((size_t)((b * CC + o * GIN + g) * HH + h)) * WW + lane * 4));
            s += Wr[o * GIN + g] * (v.x + v.y + v.z + v.w);
        }
        s = wave_sum(s);
        if (lane == 0) Xr[((((b << 9) + h) << 6)) + o] = s * (1.f / 256.f);
    }
}

// ---------- kernel 2: cosine sim (coalesced via UnT) + stable top-8 + degree (bit-identical) ----------
__global__ __launch_bounds__(256) void topk_kernel(const float* __restrict__ UnT,
                                                   float* __restrict__ topv,
                                                   int* __restrict__ topi,
                                                   float* __restrict__ deg) {
    int gid  = blockIdx.x * 256 + threadIdx.x;
    int wid  = gid >> 6;          // over B*H = 2048
    int lane = threadIdx.x & 63;
    int b = wid >> 9, h = wid & 511;
    const float* Tb = UnT + (b << 15);   // [k][h'] : 64 x 512

    float uhv = Tb[(lane << 9) + h];     // = Un[b][h][lane]

    float sim[8];
#pragma unroll
    for (int j = 0; j < 8; ++j) sim[j] = 0.f;
#pragma unroll 4
    for (int kk = 0; kk < 64; ++kk) {
        float u = __shfl(uhv, kk, 64);                 // = uh[kk]
        const float* Trow = Tb + (kk << 9);
#pragma unroll
        for (int j = 0; j < 8; ++j) sim[j] += u * Trow[lane + 64 * j];   // 4B lane stride
    }

    float vsum = 0.f;
#pragma unroll
    for (int r = 0; r < KNN8; ++r) {
        float bv = sim[0]; int bj = 0;
#pragma unroll
        for (int j = 1; j < 8; ++j) { if (sim[j] > bv) { bv = sim[j]; bj = j; } }
        float v = bv; int g = lane + 64 * bj;
#pragma unroll
        for (int off = 32; off; off >>= 1) {
            float ov = __shfl_xor(v, off, 64);
            int   og = __shfl_xor(g, off, 64);
            if (ov > v || (ov == v && og < g)) { v = ov; g = og; }
        }
        vsum += v;
        if (lane == 0) { topv[wid * KNN8 + r] = v; topi[wid * KNN8 + r] = g; }
        if ((g & 63) == lane) sim[g >> 6] = -INFINITY;
    }
    if (lane == 0) deg[wid] = vsum;
}

// ---------- kernel 3: neighbor-aggregate + GCN matmul + bias/relu (bit-identical) ----------
__global__ __launch_bounds__(64) void gcnval_kernel(const float* __restrict__ Xr,
                                                    const float* __restrict__ Wg,
                                                    const float* __restrict__ bg,
                                                    const float* __restrict__ topv,
                                                    const int* __restrict__ topi,
                                                    const float* __restrict__ deg,
                                                    float* __restrict__ yout) {
    int bh   = blockIdx.x;            // (b<<9) + h
    int b    = bh >> 9;
    int lane = threadIdx.x & 63;

    float dh = 1.0f / sqrtf(deg[bh]);
    float z = 0.f;
#pragma unroll
    for (int k = 0; k < KNN8; ++k) {
        int   i = topi[bh * KNN8 + k];
        float w = topv[bh * KNN8 + k] * dh * (1.0f / sqrtf(deg[(b << 9) + i]));
        z += w * Xr[(((b << 9) + i) << 6) + lane];
    }
    float y = 0.f;
#pragma unroll 16
    for (int c = 0; c < CRED; ++c) y += __shfl(z, c, 64) * Wg[c * CRED + lane];
    yout[(bh << 6) + lane] = fmaxf(y + bg[lane], 0.f);
}

// ---------- kernel 4: linear writer, one contiguous 1KB row per wave, nt stores (bit-identical) ----------
__global__ __launch_bounds__(256) void out_kernel(const float* __restrict__ yout,
                                                  const float* __restrict__ We,
                                                  float* __restrict__ out) {
    int gid = blockIdx.x * 256 + threadIdx.x;   // over B*C*H*64
    int row = gid >> 6;                         // (b*C + c)*H + h
    int w4  = gid & 63;
    int h = row & 511;
    int c = (row >> 9) & 255;
    int b = row >> 17;
    float val = yout[(((b << 9) + h) << 6) + (c >> 2)] * We[c];
    f4 v = {val, val, val, val};
    __builtin_nontemporal_store(v, (f4*)(out + (size_t)row * WW + w4 * 4));
}

extern "C" void kernel_launch(void* const* d_in, const int* in_sizes, int n_in,
                              void* d_out, int out_size, void* d_ws, size_t ws_size,
                              hipStream_t stream) {
    const float* x  = (const float*)d_in[0];
    const float* Uk = (const float*)d_in[1];
    const float* Wr = (const float*)d_in[2];
    const float* Wg = (const float*)d_in[3];
    const float* bg = (const float*)d_in[4];
    const float* We = (const float*)d_in[5];
    float* out = (float*)d_out;
    float* ws  = (float*)d_ws;

    float* Xr   = ws;                 // B*H*64 = 131072
    float* UnT  = ws + 131072;        // B*64*H = 131072
    float* topv = ws + 262144;        // B*H*8  = 16384
    int*   topi = (int*)(ws + 278528);// B*H*8  = 16384
    float* deg  = ws + 294912;        // B*H    = 2048
    float* yout = ws + 296960;        // B*H*64 = 131072

    hipLaunchKernelGGL(k1_kernel,      dim3(2560),   dim3(256), 0, stream, x, Wr, Uk, Xr, UnT);
    hipLaunchKernelGGL(topk_kernel,    dim3(512),    dim3(256), 0, stream, UnT, topv, topi, deg);
    hipLaunchKernelGGL(gcnval_kernel,  dim3(2048),   dim3(64),  0, stream, Xr, Wg, bg, topv, topi, deg, yout);
    hipLaunchKernelGGL(out_kernel,     dim3(131072), dim3(256), 0, stream, yout, We, out);
}